// Round 6
// baseline (836.490 us; speedup 1.0000x reference)
//
#include <hip/hip_runtime.h>
#include <stdint.h>

typedef __attribute__((ext_vector_type(8))) short v8s;
typedef __attribute__((ext_vector_type(4))) short v4s;
typedef __attribute__((ext_vector_type(4))) float v4f;

#define MFMA(a, b, c) __builtin_amdgcn_mfma_f32_16x16x32_bf16((a), (b), (c), 0, 0, 0)

__device__ __forceinline__ unsigned short f2bf(float f) {
    unsigned int u = __float_as_uint(f);
    u += 0x7fffu + ((u >> 16) & 1u);           // RNE, inputs are finite
    return (unsigned short)(u >> 16);
}
__device__ __forceinline__ float bf2f(unsigned short h) {
    return __uint_as_float(((unsigned int)h) << 16);
}

// async global->LDS, 16B per lane. LDS dest = wave-uniform base (+ lane*16 by HW).
__device__ __forceinline__ void gload16(const void* g, void* l) {
    __builtin_amdgcn_global_load_lds((const __attribute__((address_space(1))) void*)g,
                                     (__attribute__((address_space(3))) void*)l, 16, 0, 0);
}

// ---- paired-line swizzle for [128][32]bf16 arrays (8KB), 64B logical rows ----
// line = row>>1 (128B), slot(row,c) = (((row&1)<<2)|c) ^ (line&7); byte = line*128 + slot*16.
// Read address for (row, chunk c in 0..3):
__device__ __forceinline__ int pl_addr(int row, int c) {
    return ((row >> 1) << 7) + ((((((row & 1) << 2) | c)) ^ ((row >> 1) & 7)) << 4);
}
// Stage inversion: instr k (0..7, lines k*8..k*8+7), lane i: LDS byte = k*1024 + i*16.
// Global element there: t = (i&7)^(i>>3); row = 16k + 2*(i>>3) + (t>>2); colbyte = (t&3)*16.

#define NB 4
#define SEQ 4096
#define ED 1024

// ---- workspace byte offsets (peak 224 MB < proven-good 232 MB) ----
#define XHI_OFF   (0ll)
#define XLO_OFF   (33554432ll)
#define XT_OFF    (67108864ll)
#define YHI_OFF   (100663296ll)
#define YLO_OFF   (134217728ll)
#define SBUF_OFF  (167772160ll)    // 64 MB: 160M..224M
#define WQH_OFF   (222298112ll)    // scratch inside SBUF tail (dead before gemm_s)
#define WQL_OFF   (224395264ll)
#define WKH_OFF   (226492416ll)
#define WKL_OFF   (228589568ll)
#define MTH_OFF   (230686720ll)
#define MTL_OFF   (232783872ll)
#define WS_NEED   (234881024ll)    // 224 MB

// ============ prep_x: split X -> bf16 hi/lo, and transpose -> XT[b][d][s] ============
__global__ __launch_bounds__(256) void prep_x(const float* __restrict__ x,
                                              unsigned short* __restrict__ xhi,
                                              unsigned short* __restrict__ xlo,
                                              unsigned short* __restrict__ xt) {
    __shared__ float tile[64][65];
    int b = blockIdx.z, s0 = blockIdx.x * 64, d0 = blockIdx.y * 64;
    int t = threadIdx.x;
#pragma unroll
    for (int i = 0; i < 16; ++i) {
        int idx = t + i * 256;
        int r = idx >> 6, c = idx & 63;
        long gi = (long)(b * SEQ + s0 + r) * ED + d0 + c;
        float v = x[gi];
        tile[r][c] = v;
        unsigned short hi = f2bf(v);
        xhi[gi] = hi;
        xlo[gi] = f2bf(v - bf2f(hi));
    }
    __syncthreads();
#pragma unroll
    for (int i = 0; i < 16; ++i) {
        int idx = t + i * 256;
        int r = idx >> 6, c = idx & 63;   // r: local d, c: local s
        xt[(long)(b * ED + d0 + r) * SEQ + s0 + c] = f2bf(tile[c][r]);
    }
}

// ============ prep_w2: split Wq, Wk (row-major, no transpose) into bf16 hi/lo ============
__global__ __launch_bounds__(256) void prep_w2(const float* __restrict__ wq,
                                               const float* __restrict__ wk,
                                               unsigned short* __restrict__ wqh,
                                               unsigned short* __restrict__ wql,
                                               unsigned short* __restrict__ wkh,
                                               unsigned short* __restrict__ wkl) {
    const float* w = blockIdx.z ? wk : wq;
    unsigned short* oh = blockIdx.z ? wkh : wqh;
    unsigned short* ol = blockIdx.z ? wkl : wql;
    long idx = ((long)blockIdx.x * 256 + threadIdx.x) * 4;
    v4f v = *(const v4f*)(w + idx);
    v4s ph, pl;
#pragma unroll
    for (int e = 0; e < 4; ++e) {
        unsigned short hi = f2bf(v[e]);
        ph[e] = (short)hi;
        pl[e] = (short)f2bf(v[e] - bf2f(hi));
    }
    *(v4s*)(oh + idx) = ph;
    *(v4s*)(ol + idx) = pl;
}

// ============ gemm_m: MT[e'][e] = sum_f Wk[e'][f] * Wq[e][f]  (4-pass split, old loop) ====
__global__ __launch_bounds__(256, 2) void gemm_m(const unsigned short* __restrict__ ah,
                                                 const unsigned short* __restrict__ al,
                                                 const unsigned short* __restrict__ bh,
                                                 const unsigned short* __restrict__ bl,
                                                 unsigned short* __restrict__ ch,
                                                 unsigned short* __restrict__ cl) {
    __shared__ __align__(16) unsigned char lds[65536];
    int m0 = blockIdx.x * 128, n0 = blockIdx.y * 128;
    int tid = threadIdx.x, lane = tid & 63, wave = tid >> 6;
    int mo = (wave & 1) * 64, no = (wave >> 1) * 64;
    int lr = lane >> 3;
    int scol = (((lane & 7) ^ lr) << 4);
    v4f vzero = {0.f, 0.f, 0.f, 0.f};
    v4f acc[4][4];
#pragma unroll
    for (int i = 0; i < 4; ++i)
#pragma unroll
        for (int j = 0; j < 4; ++j) acc[i][j] = vzero;
    int cb0 = 16 * (lane >> 4);

    for (int ks = 0; ks < 16; ++ks) {
        __syncthreads();
#pragma unroll
        for (int j = 0; j < 4; ++j) {
            int c = j * 4 + wave;
            int row = c * 8 + lr;
            long ga = ((long)(m0 + row) * ED + ks * 64) * 2 + scol;
            long gb = ((long)(n0 + row) * ED + ks * 64) * 2 + scol;
            unsigned loff = c * 1024;
            gload16((const unsigned char*)ah + ga, lds + loff);
            gload16((const unsigned char*)al + ga, lds + 16384 + loff);
            gload16((const unsigned char*)bh + gb, lds + 32768 + loff);
            gload16((const unsigned char*)bl + gb, lds + 49152 + loff);
        }
        __syncthreads();
#pragma unroll
        for (int kk = 0; kk < 2; ++kk) {
            v8s fah[4], fal[4], fbh[4], fbl[4];
#pragma unroll
            for (int i = 0; i < 4; ++i) {
                int ra = mo + i * 16 + (lane & 15);
                int ca = (kk * 64 + cb0) ^ ((ra & 7) << 4);
                fah[i] = *(const v8s*)(lds +         ra * 128 + ca);
                fal[i] = *(const v8s*)(lds + 16384 + ra * 128 + ca);
                int rb = no + i * 16 + (lane & 15);
                int cbb = (kk * 64 + cb0) ^ ((rb & 7) << 4);
                fbh[i] = *(const v8s*)(lds + 32768 + rb * 128 + cbb);
                fbl[i] = *(const v8s*)(lds + 49152 + rb * 128 + cbb);
            }
#pragma unroll
            for (int i = 0; i < 4; ++i)
#pragma unroll
                for (int j = 0; j < 4; ++j) {
                    acc[i][j] = MFMA(fah[i], fbh[j], acc[i][j]);
                    acc[i][j] = MFMA(fah[i], fbl[j], acc[i][j]);
                    acc[i][j] = MFMA(fal[i], fbh[j], acc[i][j]);
                    acc[i][j] = MFMA(fal[i], fbl[j], acc[i][j]);
                }
        }
    }
#pragma unroll
    for (int i = 0; i < 4; ++i)
#pragma unroll
        for (int j = 0; j < 4; ++j)
#pragma unroll
            for (int r = 0; r < 4; ++r) {
                int row = m0 + mo + i * 16 + (lane >> 4) * 4 + r;
                int col = n0 + no + j * 16 + (lane & 15);
                float v = acc[i][j][r];
                unsigned short hi = f2bf(v);
                long o = (long)row * ED + col;
                ch[o] = hi;
                cl[o] = f2bf(v - bf2f(hi));
            }
}

// ============ split-GEMM core, BK=32 double-buffered 2-phase pipeline ============
// C = A x B^T over K=1024 (3 mfma passes), A rows at arow0+m0, B rows at brow0+n0,
// both row-stride 2048B. Emits either split-bf16 C (gemm_y) or scaled fp32 S (gemm_s).
template <int EMIT_SPLIT>
__device__ __forceinline__ void split_gemm_bk32(const unsigned char* ah, const unsigned char* al,
                                                const unsigned char* bh, const unsigned char* bl,
                                                long arow0, long brow0,
                                                unsigned short* ch, unsigned short* cl,
                                                float* sbuf, float sscale,
                                                unsigned char* lds) {
    int m0 = blockIdx.x * 128, n0 = blockIdx.y * 128;
    int tid = threadIdx.x, lane = tid & 63, wave = tid >> 6;
    int mo = (wave & 1) * 64, no = (wave >> 1) * 64;
    v4f vzero = {0.f, 0.f, 0.f, 0.f};
    v4f acc[4][4];
#pragma unroll
    for (int i = 0; i < 4; ++i)
#pragma unroll
        for (int j = 0; j < 4; ++j) acc[i][j] = vzero;

    // stage-side precomputed lane terms (paired-line inversion)
    int t2 = (lane & 7) ^ (lane >> 3);
    int rsub = 2 * (lane >> 3) + (t2 >> 2);    // row within 16-row instr group
    int gcb = (t2 & 3) << 4;                   // source col byte within 64B K-slab
    int cfr = lane >> 4;                       // fragment K-chunk 0..3

#define STAGE32(ks, buf)                                                              \
    {                                                                                 \
        unsigned lb = (buf) * 32768u;                                                 \
        long ko = (long)(ks) * 64 + gcb;                                              \
        _Pragma("unroll")                                                             \
        for (int j = 0; j < 2; ++j) {                                                 \
            int k = j * 4 + wave;                                                     \
            int row = 16 * k + rsub;                                                  \
            long ga = (arow0 + m0 + row) * 2048 + ko;                                 \
            long gb = (brow0 + n0 + row) * 2048 + ko;                                 \
            unsigned loff = lb + k * 1024;                                            \
            gload16(ah + ga, lds + loff);                                             \
            gload16(al + ga, lds + 8192 + loff);                                      \
            gload16(bh + gb, lds + 16384 + loff);                                     \
            gload16(bl + gb, lds + 24576 + loff);                                     \
        }                                                                             \
    }

    STAGE32(0, 0);
    __syncthreads();
    for (int ks = 0; ks < 32; ++ks) {
        unsigned lb = (ks & 1) * 32768u;
        if (ks + 1 < 32) STAGE32(ks + 1, (ks + 1) & 1);
        v8s fah[4], fal[4], fbh[4], fbl[4];
#pragma unroll
        for (int i = 0; i < 4; ++i) {
            int ra = mo + i * 16 + (lane & 15);
            int pa = pl_addr(ra, cfr);
            fah[i] = *(const v8s*)(lds + lb +         pa);
            fal[i] = *(const v8s*)(lds + lb + 8192  + pa);
            int rb = no + i * 16 + (lane & 15);
            int pb = pl_addr(rb, cfr);
            fbh[i] = *(const v8s*)(lds + lb + 16384 + pb);
            fbl[i] = *(const v8s*)(lds + lb + 24576 + pb);
        }
#pragma unroll
        for (int i = 0; i < 4; ++i)
#pragma unroll
            for (int j = 0; j < 4; ++j) {
                acc[i][j] = MFMA(fah[i], fbh[j], acc[i][j]);
                acc[i][j] = MFMA(fah[i], fbl[j], acc[i][j]);
                acc[i][j] = MFMA(fal[i], fbh[j], acc[i][j]);
            }
        __syncthreads();   // implicit vmcnt(0): next-tile loads landed; cur reads done
    }
#undef STAGE32

#pragma unroll
    for (int i = 0; i < 4; ++i)
#pragma unroll
        for (int j = 0; j < 4; ++j)
#pragma unroll
            for (int r = 0; r < 4; ++r) {
                int row = m0 + mo + i * 16 + (lane >> 4) * 4 + r;
                int col = n0 + no + j * 16 + (lane & 15);
                float v = acc[i][j][r];
                if (EMIT_SPLIT) {
                    unsigned short hi = f2bf(v);
                    long o = (arow0 + row) * (long)ED + col;
                    ch[o] = hi;
                    cl[o] = f2bf(v - bf2f(hi));
                } else {
                    sbuf[(long)row * SEQ + col] = v * sscale;
                }
            }
}

// ============ gemm_y: Y = X x M (split out), BK=32 pipelined ============
__global__ __launch_bounds__(256, 2) void gemm_y(const unsigned short* __restrict__ ah,
                                                 const unsigned short* __restrict__ al,
                                                 const unsigned short* __restrict__ bh,
                                                 const unsigned short* __restrict__ bl,
                                                 unsigned short* __restrict__ ch,
                                                 unsigned short* __restrict__ cl) {
    __shared__ __align__(16) unsigned char lds[65536];
    split_gemm_bk32<1>((const unsigned char*)ah, (const unsigned char*)al,
                       (const unsigned char*)bh, (const unsigned char*)bl,
                       0, 0, ch, cl, nullptr, 1.0f, lds);
}

// ============ gemm_s: S = (Y X^T)/32 for one batch (fp32 out), BK=32 pipelined ============
__global__ __launch_bounds__(256, 2) void gemm_s(const unsigned short* __restrict__ qhi,
                                                 const unsigned short* __restrict__ qlo,
                                                 const unsigned short* __restrict__ khi,
                                                 const unsigned short* __restrict__ klo,
                                                 float* __restrict__ sbuf, int b) {
    __shared__ __align__(16) unsigned char lds[65536];
    split_gemm_bk32<0>((const unsigned char*)qhi, (const unsigned char*)qlo,
                       (const unsigned char*)khi, (const unsigned char*)klo,
                       (long)b * SEQ, (long)b * SEQ, nullptr, nullptr, sbuf, 0.03125f, lds);
}

// ============ softmax_rows: P = exp(S-m)/l, bf16, packed in-place (first 8KB of row) ============
__global__ __launch_bounds__(256) void softmax_rows(float* __restrict__ sbuf) {
    int row = blockIdx.x * 4 + (threadIdx.x >> 6);
    int lane = threadIdx.x & 63;
    float* base = sbuf + (long)row * SEQ;
    v4f v[16];
    float m = -INFINITY;
#pragma unroll
    for (int j = 0; j < 16; ++j) {
        v[j] = *(const v4f*)(base + j * 256 + lane * 4);
#pragma unroll
        for (int e = 0; e < 4; ++e) m = fmaxf(m, v[j][e]);
    }
#pragma unroll
    for (int o = 1; o < 64; o <<= 1) m = fmaxf(m, __shfl_xor(m, o));
    float s = 0.f;
#pragma unroll
    for (int j = 0; j < 16; ++j)
#pragma unroll
        for (int e = 0; e < 4; ++e) {
            float p = __expf(v[j][e] - m);
            s += p;
            v[j][e] = p;
        }
#pragma unroll
    for (int o = 1; o < 64; o <<= 1) s += __shfl_xor(s, o);
    float inv = 1.0f / s;
    unsigned short* ob = (unsigned short*)base;
#pragma unroll
    for (int j = 0; j < 16; ++j) {
        v4s pk;
#pragma unroll
        for (int e = 0; e < 4; ++e) pk[e] = (short)f2bf(v[j][e] * inv);
        *(v4s*)(ob + j * 256 + lane * 4) = pk;
    }
}

// ============ gemm_pv: O[q][d] = P X, BK=64 double-buffered 2-phase ============
__global__ __launch_bounds__(256, 2) void gemm_pv(const float* __restrict__ sbuf,
                                                  const unsigned short* __restrict__ xt,
                                                  float* __restrict__ out, int b) {
    __shared__ __align__(16) unsigned char lds[65536];   // 2 x {A 16KB, B 16KB}
    int m0 = blockIdx.x * 128, n0 = blockIdx.y * 128;
    int tid = threadIdx.x, lane = tid & 63, wave = tid >> 6;
    int mo = (wave & 1) * 64, no = (wave >> 1) * 64;
    const unsigned char* pbytes = (const unsigned char*)sbuf;
    int lr = lane >> 3;
    int scol = (((lane & 7) ^ lr) << 4);
    v4f vzero = {0.f, 0.f, 0.f, 0.f};
    v4f acc[4][4];
#pragma unroll
    for (int i = 0; i < 4; ++i)
#pragma unroll
        for (int j = 0; j < 4; ++j) acc[i][j] = vzero;
    int cb0 = 16 * (lane >> 4);

#define STAGEPV(ks, buf)                                                              \
    {                                                                                 \
        unsigned lb = (buf) * 32768u;                                                 \
        _Pragma("unroll")                                                             \
        for (int j = 0; j < 4; ++j) {                                                 \
            int c = j * 4 + wave;                                                     \
            int row = c * 8 + lr;                                                     \
            long ga = (long)(m0 + row) * 16384 + (ks) * 128 + scol;                   \
            long gb = ((long)(b * ED + n0 + row) * SEQ + (ks) * 64) * 2 + scol;       \
            unsigned loff = lb + c * 1024;                                            \
            gload16(pbytes + ga, lds + loff);                                         \
            gload16((const unsigned char*)xt + gb, lds + 16384 + loff);               \
        }                                                                             \
    }

    STAGEPV(0, 0);
    __syncthreads();
    for (int ks = 0; ks < 64; ++ks) {
        unsigned lb = (ks & 1) * 32768u;
        if (ks + 1 < 64) STAGEPV(ks + 1, (ks + 1) & 1);
#pragma unroll
        for (int kk = 0; kk < 2; ++kk) {
            v8s fa[4], fb[4];
#pragma unroll
            for (int i = 0; i < 4; ++i) {
                int ra = mo + i * 16 + (lane & 15);
                int ca = (kk * 64 + cb0) ^ ((ra & 7) << 4);
                fa[i] = *(const v8s*)(lds + lb +         ra * 128 + ca);
                int rb = no + i * 16 + (lane & 15);
                int cbb = (kk * 64 + cb0) ^ ((rb & 7) << 4);
                fb[i] = *(const v8s*)(lds + lb + 16384 + rb * 128 + cbb);
            }
#pragma unroll
            for (int i = 0; i < 4; ++i)
#pragma unroll
                for (int j = 0; j < 4; ++j)
                    acc[i][j] = MFMA(fa[i], fb[j], acc[i][j]);
        }
        __syncthreads();
    }
#undef STAGEPV

#pragma unroll
    for (int i = 0; i < 4; ++i)
#pragma unroll
        for (int j = 0; j < 4; ++j)
#pragma unroll
            for (int r = 0; r < 4; ++r) {
                int row = m0 + mo + i * 16 + (lane >> 4) * 4 + r;
                int col = n0 + no + j * 16 + (lane & 15);
                out[(long)(b * SEQ + row) * ED + col] = acc[i][j][r];
            }
}

extern "C" void kernel_launch(void* const* d_in, const int* in_sizes, int n_in,
                              void* d_out, int out_size, void* d_ws, size_t ws_size,
                              hipStream_t stream) {
    const float* x  = (const float*)d_in[0];
    const float* wq = (const float*)d_in[1];
    const float* wk = (const float*)d_in[2];
    unsigned char* ws = (unsigned char*)d_ws;
    unsigned short* xhi = (unsigned short*)(ws + XHI_OFF);
    unsigned short* xlo = (unsigned short*)(ws + XLO_OFF);
    unsigned short* xt  = (unsigned short*)(ws + XT_OFF);
    unsigned short* yhi = (unsigned short*)(ws + YHI_OFF);
    unsigned short* ylo = (unsigned short*)(ws + YLO_OFF);
    float*          sbuf= (float*)(ws + SBUF_OFF);
    unsigned short* wqh = (unsigned short*)(ws + WQH_OFF);
    unsigned short* wql = (unsigned short*)(ws + WQL_OFF);
    unsigned short* wkh = (unsigned short*)(ws + WKH_OFF);
    unsigned short* wkl = (unsigned short*)(ws + WKL_OFF);
    unsigned short* mth = (unsigned short*)(ws + MTH_OFF);
    unsigned short* mtl = (unsigned short*)(ws + MTL_OFF);

    prep_x<<<dim3(64, 16, 4), 256, 0, stream>>>(x, xhi, xlo, xt);
    prep_w2<<<dim3(1024, 1, 2), 256, 0, stream>>>(wq, wk, wqh, wql, wkh, wkl);
    gemm_m<<<dim3(8, 8), 256, 0, stream>>>(wkh, wkl, wqh, wql, mth, mtl);
    gemm_y<<<dim3(128, 8), 256, 0, stream>>>(xhi, xlo, mth, mtl, yhi, ylo);
    for (int b = 0; b < NB; ++b) {
        gemm_s<<<dim3(32, 32), 256, 0, stream>>>(yhi, ylo, xhi, xlo, sbuf, b);
        softmax_rows<<<1024, 256, 0, stream>>>(sbuf);
        gemm_pv<<<dim3(32, 8), 256, 0, stream>>>(sbuf, xt, (float*)d_out, b);
    }
}